// Round 11
// baseline (103.455 us; speedup 1.0000x reference)
//
#include <hip/hip_runtime.h>
#include <math.h>

#define B_IMG 16
#define N_PROP 2048
#define C_CLS 3
#define K_OUT 100
#define NTHREADS 1024
#define NWAVES (NTHREADS / 64)
#define NBLK64 (N_PROP / 64)
#define NUNITS (B_IMG * N_PROP)           // 32768 (img,n) units
#define NTHA 512                          // presort kernel threads
#define RUN 1024                          // presorted run length

__device__ __forceinline__ unsigned long long shfl_xor_u64(unsigned long long v, int lx) {
    unsigned int lo = (unsigned int)__shfl_xor((int)(unsigned int)(v & 0xffffffffull), lx, 64);
    unsigned int hi = (unsigned int)__shfl_xor((int)(unsigned int)(v >> 32), lx, 64);
    return ((unsigned long long)hi << 32) | (unsigned long long)lo;
}
__device__ __forceinline__ float readlane_f(float v, int l) {
    return __int_as_float(__builtin_amdgcn_readlane(__float_as_int(v), l));
}
__device__ __forceinline__ unsigned long long readlane_u64(unsigned long long v, int l) {
    unsigned int lo = (unsigned int)__builtin_amdgcn_readlane((int)(unsigned int)(v & 0xffffffffull), l);
    unsigned int hi = (unsigned int)__builtin_amdgcn_readlane((int)(unsigned int)(v >> 32), l);
    return ((unsigned long long)hi << 32) | (unsigned long long)lo;
}
// Exact replacement for: RN(inter / max(uni,1e-8f)) > 0.5f
// RN(a/b) > 0.5 <=> a/b > 0.5+2^-25 <=> 2a > b*(1+2^-24); b*(1+2^-24) exact in
// double (24+25=49 < 53 bits). Bit-equivalent to the reference decision.
__device__ __forceinline__ bool iou_gt_half(float inter, float uni) {
    double b = (double)fmaxf(uni, 1e-8f);
    return (double)inter * 2.0 > b * 0x1.000001p0;
}
__device__ __forceinline__ float parse_imgf(int raw) {
    return (raw > 0 && raw < 1000000) ? (float)raw : __int_as_float(raw);
}

// ---------------- kernel A: fused decode + 1024-run presort ----------------
// 64 blocks: one per (img,cls,half). Sorts its run descending iff
// (run_start & 1024)==0 (mirrored network via `flip`) == state of the
// standard full bitonic network after stage k=1024.
__global__ __launch_bounds__(NTHA)
void decode_sort_kernel(const float* __restrict__ class_logit,
                        const float* __restrict__ box_reg,
                        const float* __restrict__ proposal,
                        const int* __restrict__ image_shape_p,
                        unsigned long long* __restrict__ wskey,   // [2][NUNITS]
                        float2* __restrict__ wbox)                // [2][NUNITS]
{
#pragma clang fp contract(off)
    __shared__ unsigned long long skey[RUN];

    const int tid = threadIdx.x;
    const int lane = tid & 63;
    const int wid = tid >> 6;
    const int u = blockIdx.x >> 1;
    const int q = blockIdx.x & 1;
    const int img = u >> 1;
    const int cls = u & 1;                       // fg class index-1
    const bool flip = (q & 1) != 0;              // odd half sorts ascending
    const int off = q * RUN;
    const size_t base = (size_t)cls * NUNITS + (size_t)img * N_PROP;
    const float imgf = parse_imgf(image_shape_p[0]);

    // decode proposals for this class (identical fp sequence to reference)
    for (int i = tid; i < RUN; i += NTHA) {
        const int n = off + i;
        const size_t g = (size_t)img * N_PROP + n;
        const float* lg = class_logit + g * C_CLS;
        float l0 = lg[0], l1 = lg[1], l2 = lg[2];
        float mx = fmaxf(l0, fmaxf(l1, l2));
        float e0 = (float)exp((double)(l0 - mx));
        float e1 = (float)exp((double)(l1 - mx));
        float e2 = (float)exp((double)(l2 - mx));
        float denom = (e0 + e1) + e2;
        float score = ((cls == 0) ? e1 : e2) / denom;

        const float* dr = box_reg + g * (2 * C_CLS) + 2 * (cls + 1);
        float dx = dr[0];                       // / WX == 1
        float dw = fminf(dr[1], 4.0f);          // / WW == 1, clamp 4
        const float* pp = proposal + g * 2;
        float pA = pp[0], pB = pp[1];
        float w = pB - pA;
        float ctr = pA + 0.5f * w;
        float tt = dx * w;
        float pc = tt + ctr;
        float pw = (float)exp((double)dw) * w;
        float half = 0.5f * pw;
        float lo = pc - half;
        float hi = pc + half;
        lo = fminf(fmaxf(lo, 0.0f), imgf);
        hi = fminf(fmaxf(hi, 0.0f), imgf);
        bool valid = ((hi - lo) >= 10.0f) && (score >= 0.05f);
        float ms = valid ? score : -1e9f;
        wbox[base + n] = make_float2(lo, hi);
        unsigned int uu = __float_as_uint(ms);
        unsigned int e = (uu & 0x80000000u) ? ~uu : (uu | 0x80000000u); // order-preserving
        skey[i] = ((unsigned long long)e << 32) |
                  (unsigned long long)(0xFFFFFFFFu - (unsigned int)n);  // idx asc on ties
    }
    __syncthreads();

    // hybrid reg/LDS bitonic over the 1024-run (direction mirrored by flip)
    const int p0 = (wid << 7) | (lane << 1);    // == 2*tid, wave-contiguous spans
    const int p1 = p0 | 1;
    unsigned long long r0 = skey[p0], r1 = skey[p1];

    auto pass_inreg = [&](int k, int j) {
        bool desc = (((p0 & k) == 0) != flip);
        if (j == 1) {
            bool sw = desc ? (r0 < r1) : (r0 > r1);
            if (sw) { unsigned long long t = r0; r0 = r1; r1 = t; }
        } else {
            int lx = j >> 1;
            unsigned long long o0 = shfl_xor_u64(r0, lx);
            unsigned long long o1 = shfl_xor_u64(r1, lx);
            bool lower = ((p0 & j) == 0);
            bool takeMax = (lower == desc);
            r0 = takeMax ? (r0 > o0 ? r0 : o0) : (r0 < o0 ? r0 : o0);
            r1 = takeMax ? (r1 > o1 ? r1 : o1) : (r1 < o1 ? r1 : o1);
        }
    };

    for (int k = 2; k <= 128; k <<= 1)
        for (int j = k >> 1; j >= 1; j >>= 1)
            pass_inreg(k, j);

    for (int k = 256; k <= RUN; k <<= 1) {
        skey[p0] = r0; skey[p1] = r1;
        __syncthreads();
        for (int j = k >> 1; j >= 128; j >>= 1) {
            int i = ((tid & ~(j - 1)) << 1) | (tid & (j - 1));
            int part = i | j;
            unsigned long long a = skey[i], b = skey[part];
            bool desc_blk = (((i & k) == 0) != flip);
            bool sw = desc_blk ? (a < b) : (a > b);
            if (sw) { skey[i] = b; skey[part] = a; }
            __syncthreads();
        }
        r0 = skey[p0]; r1 = skey[p1];
        for (int j = 64; j >= 1; j >>= 1)
            pass_inreg(k, j);
    }
    wskey[base + off + p0] = r0;
    wskey[base + off + p1] = r1;
}

// ---------------- kernel B: final merge (k=2048) + W=128 matrix NMS + top-K ----------------
__global__ __launch_bounds__(NTHREADS)
void roiheads_kernel(const unsigned long long* __restrict__ wskey,
                     const float2* __restrict__ wbox,
                     float* __restrict__ out)
{
#pragma clang fp contract(off)
    __shared__ unsigned long long skey[N_PROP];     // 16 KB sort keys
    __shared__ float slo[N_PROP], shi[N_PROP];      // boxes in sorted order
    __shared__ unsigned char keep[N_PROP];
    __shared__ unsigned short alv[2][N_PROP];       // alive (undecided) sorted positions
    __shared__ float clo[128], chi[128];            // this round's kept boxes
    __shared__ unsigned long long sup0[128], sup1[128]; // window suppression matrix
    __shared__ unsigned long long kmask[NBLK64];
    __shared__ int wsum[NWAVES];
    __shared__ int sh_nvalid;

    const int tid = threadIdx.x;
    const int lane = tid & 63;
    const int wid = tid >> 6;
    const int img = blockIdx.x >> 1;
    const int cls = blockIdx.x & 1;
    const size_t base = (size_t)cls * NUNITS + (size_t)img * N_PROP;

    if (tid == 0) sh_nvalid = 0;

    const int p0 = (wid << 7) | (lane << 1);   // == 2*tid
    const int p1 = p0 | 1;

    unsigned long long r0 = wskey[base + p0];  // coalesced 16B/thread
    unsigned long long r1 = wskey[base + p1];

    auto pass_inreg = [&](int k, int j) {
        if (j == 1) {
            bool desc = ((p0 & k) == 0);
            bool sw = desc ? (r0 < r1) : (r0 > r1);
            if (sw) { unsigned long long t = r0; r0 = r1; r1 = t; }
        } else {
            int lx = j >> 1;
            unsigned long long o0 = shfl_xor_u64(r0, lx);
            unsigned long long o1 = shfl_xor_u64(r1, lx);
            bool desc = ((p0 & k) == 0);
            bool lower = ((p0 & j) == 0);
            bool takeMax = (lower == desc);
            r0 = takeMax ? (r0 > o0 ? r0 : o0) : (r0 < o0 ? r0 : o0);
            r1 = takeMax ? (r1 > o1 ? r1 : o1) : (r1 < o1 ? r1 : o1);
        }
    };

    // only the final merge stage remains: 1024-runs arrive presorted in
    // alternating directions (network state after stage k=1024).
    {
        const int k = N_PROP;
        skey[p0] = r0; skey[p1] = r1;
        __syncthreads();
        for (int j = k >> 1; j >= 128; j >>= 1) {
            int i = ((tid & ~(j - 1)) << 1) | (tid & (j - 1));
            int part = i | j;
            unsigned long long a = skey[i], b = skey[part];
            bool desc_blk = ((i & k) == 0);
            bool sw = desc_blk ? (a < b) : (a > b);
            if (sw) { skey[i] = b; skey[part] = a; }
            __syncthreads();
        }
        r0 = skey[p0]; r1 = skey[p1];
        for (int j = 64; j >= 1; j >>= 1)
            pass_inreg(k, j);
    }
    skey[p0] = r0; skey[p1] = r1;
    __syncthreads();

    // ---- gather sorted boxes (from ws via L2), count valid, init alive list ----
    for (int i = tid; i < N_PROP; i += NTHREADS) {
        unsigned long long kk = skey[i];
        unsigned int e = (unsigned int)(kk >> 32);
        unsigned int sb = (e & 0x80000000u) ? (e & 0x7FFFFFFFu) : ~e;
        float s = __uint_as_float(sb);
        unsigned int n = 0xFFFFFFFFu - (unsigned int)(kk & 0xFFFFFFFFull);
        float2 bx = wbox[base + n];
        slo[i] = bx.x;
        shi[i] = bx.y;
        keep[i] = 0;
        bool v = (s > -5e8f);    // keep0 = s > 0.5*NEG  (valid items sort first)
        unsigned long long mb = __ballot(v);
        if (lane == 0) atomicAdd(&sh_nvalid, __popcll(mb));
        alv[0][i] = (unsigned short)i;
    }
    __syncthreads();

    int na = sh_nvalid;
    int cur = 0;
    int tk = 0;
    const unsigned long long below = (1ull << lane) - 1ull;

    // ---- greedy NMS: W=128 window, register-built suppression matrix ----
    while (na > 0) {
        const int m = (na < 128) ? na : 128;

        // (a) window boxes into registers (each wave holds all 128)
        unsigned short cp0 = alv[cur][lane];
        unsigned short cp1 = alv[cur][64 + lane];
        bool in0 = (lane < m), in1 = (64 + lane < m);
        float q0l = in0 ? slo[cp0] : 0.0f, q0h = in0 ? shi[cp0] : 0.0f;
        float q1l = in1 ? slo[cp1] : 0.0f, q1h = in1 ? shi[cp1] : 0.0f;

        // (b) build 128x128 suppression matrix: 16 row-half units per wave,
        // rows via readlane (no LDS), cols from registers.
#pragma unroll
        for (int i = 0; i < 16; ++i) {
            int u = (wid << 4) | i;
            int r = u >> 1, h = u & 1;
            unsigned long long row = 0;
            if (r < m && (((h << 6) | 63) > r)) {
                float rl = readlane_f((r < 64) ? q0l : q1l, r & 63);
                float rh = readlane_f((r < 64) ? q0h : q1h, r & 63);
                float ql = h ? q1l : q0l, qh = h ? q1h : q0h;
                bool inq = h ? in1 : in0;
                float inter = fmaxf(fminf(rh, qh) - fmaxf(rl, ql), 0.0f);
                float uni = (rh - rl) + (qh - ql) - inter;   // w_r + w_c (commutative)
                int col = (h << 6) | lane;
                bool kill = inq && (col > r) && iou_gt_half(inter, uni);
                row = __ballot(kill);
            }
            if (lane == 0) { if (h) sup1[r] = row; else sup0[r] = row; }
        }
        __syncthreads();

        // (c) scalar greedy mask recurrence (redundant per wave; pops = kept only)
        unsigned long long rw00 = sup0[lane];       // row lane,    cols 0-63
        unsigned long long rw01 = sup1[lane];       // row lane,    cols 64-127
        unsigned long long rw11 = sup1[64 + lane];  // row 64+lane, cols 64-127
        unsigned long long A0 = (m >= 64) ? ~0ull : ((1ull << m) - 1ull);
        unsigned long long A1 = (m > 64) ? ((m >= 128) ? ~0ull : ((1ull << (m - 64)) - 1ull)) : 0ull;
        unsigned long long k0 = 0, k1 = 0;
        while (A0) {
            int c = __builtin_ctzll(A0);
            k0 |= (1ull << c);
            A0 &= ~(readlane_u64(rw00, c) | (1ull << c));
            A1 &= ~readlane_u64(rw01, c);
        }
        while (A1) {
            int c = __builtin_ctzll(A1);
            k1 |= (1ull << c);
            A1 &= ~(readlane_u64(rw11, c) | (1ull << c));
        }
        const int cnt0 = __popcll(k0);
        const int cnt = cnt0 + __popcll(k1);

        // (d) waves 0/1 mark kept + build compact kept-box list (from registers)
        if (wid == 0) {
            bool alive = in0 && ((k0 >> lane) & 1ull);
            if (alive) {
                keep[cp0] = 1;
                int rank = __popcll(k0 & below);
                clo[rank] = q0l; chi[rank] = q0h;
            }
        } else if (wid == 1) {
            bool alive = in1 && ((k1 >> lane) & 1ull);
            if (alive) {
                keep[cp1] = 1;
                int rank = cnt0 + __popcll(k1 & below);
                clo[rank] = q1l; chi[rank] = q1h;
            }
        }
        __syncthreads();
        tk += cnt;
        if (tk >= K_OUT) break;   // later decisions provably unused

        // (e) sweep remainder vs this round's kept (registers + readlane)
        float kl0 = 0.0f, kh0 = 0.0f, kl1 = 0.0f, kh1 = 0.0f;
        if (lane < cnt) { kl0 = clo[lane]; kh0 = chi[lane]; }
        if (64 + lane < cnt) { kl1 = clo[64 + lane]; kh1 = chi[64 + lane]; }
        const int c1 = (cnt < 64) ? cnt : 64;
        int base2 = 0;
        for (int start = m; start < na; start += NTHREADS) {
            int t2 = start + tid;
            unsigned short qq = 0;
            bool surv = false;
            if (t2 < na) {
                qq = alv[cur][t2];
                float qlo = slo[qq], qhi = shi[qq];
                float qw = qhi - qlo;
                bool dead = false;
                for (int r = 0; r < c1; ++r) {
                    float cl = readlane_f(kl0, r);
                    float ch = readlane_f(kh0, r);
                    float inter = fmaxf(fminf(qhi, ch) - fmaxf(qlo, cl), 0.0f);
                    float uni = qw + (ch - cl) - inter;
                    dead |= iou_gt_half(inter, uni);
                }
                for (int r = 64; r < cnt; ++r) {
                    float cl = readlane_f(kl1, r - 64);
                    float ch = readlane_f(kh1, r - 64);
                    float inter = fmaxf(fminf(qhi, ch) - fmaxf(qlo, cl), 0.0f);
                    float uni = qw + (ch - cl) - inter;
                    dead |= iou_gt_half(inter, uni);
                }
                surv = !dead;
            }
            unsigned long long mb = __ballot(surv);
            if (lane == 0) wsum[wid] = __popcll(mb);
            __syncthreads();
            int off2 = base2, tot = base2;
            for (int w2 = 0; w2 < NWAVES; ++w2) {
                int c2 = wsum[w2];
                if (w2 < wid) off2 += c2;
                tot += c2;
            }
            if (surv) alv[cur ^ 1][off2 + __popcll(mb & below)] = qq;
            base2 = tot;
            __syncthreads();
        }
        na = base2;
        cur ^= 1;
    }

    // ---- top-K fill (reproduces lax.top_k tie-breaking exactly) ----
    for (int blk = wid; blk < NBLK64; blk += NWAVES) {
        bool kk = keep[blk * 64 + lane] != 0;
        unsigned long long mb = __ballot(kk);
        if (lane == 0) kmask[blk] = mb;
    }
    __syncthreads();
    {
        float* outp = out + (((size_t)img * 2 + cls) * K_OUT) * 3;
        for (int blk = wid; blk < NBLK64; blk += NWAVES) {
            int kc = 0, nc = 0, nk = 0;
            for (int b = 0; b < NBLK64; ++b) {
                int pc = __popcll(kmask[b]);
                nk += pc;
                if (b < blk) { kc += pc; nc += 64 - pc; }
            }
            if (kc >= K_OUT && nk + nc >= K_OUT && nc >= K_OUT) continue;
            int p = blk * 64 + lane;
            unsigned long long mb = kmask[blk];
            bool k = (mb >> lane) & 1ull;
            int rk = kc + __popcll(mb & below);
            int rn = nc + __popcll((~mb) & below);
            if (k) {
                if (rk < K_OUT) {
                    unsigned long long kk2 = skey[p];
                    unsigned int e = (unsigned int)(kk2 >> 32);
                    unsigned int sb = (e & 0x80000000u) ? (e & 0x7FFFFFFFu) : ~e;
                    outp[rk * 3 + 0] = slo[p];
                    outp[rk * 3 + 1] = shi[p];
                    outp[rk * 3 + 2] = __uint_as_float(sb);
                }
            } else {
                int oi = nk + rn;
                if (oi < K_OUT) {
                    outp[oi * 3 + 0] = slo[p];
                    outp[oi * 3 + 1] = shi[p];
                    outp[oi * 3 + 2] = -1e9f;
                }
            }
        }
    }
}

extern "C" void kernel_launch(void* const* d_in, const int* in_sizes, int n_in,
                              void* d_out, int out_size, void* d_ws, size_t ws_size,
                              hipStream_t stream) {
    const float* class_logit = (const float*)d_in[0];
    const float* box_reg     = (const float*)d_in[1];
    const float* prop        = (const float*)d_in[2];
    const int*   image_shape = (const int*)d_in[3];
    float* out = (float*)d_out;

    unsigned long long* wskey = (unsigned long long*)d_ws;            // 512 KB
    float2* wbox = (float2*)((char*)d_ws + 2 * NUNITS * sizeof(unsigned long long));

    decode_sort_kernel<<<dim3(B_IMG * 2 * 2), dim3(NTHA), 0, stream>>>(
        class_logit, box_reg, prop, image_shape, wskey, wbox);
    roiheads_kernel<<<dim3(B_IMG * 2), dim3(NTHREADS), 0, stream>>>(
        wskey, wbox, out);
}

// Round 12
// 96.450 us; speedup vs baseline: 1.0726x; 1.0726x over previous
//
#include <hip/hip_runtime.h>
#include <math.h>

#define B_IMG 16
#define N_PROP 2048
#define C_CLS 3
#define K_OUT 100
#define NTHREADS 1024
#define NWAVES (NTHREADS / 64)
#define NBLK64 (N_PROP / 64)
#define NUNITS (B_IMG * N_PROP)           // 32768 (img,n) units
#define NTHA 256                          // presort kernel threads
#define RUN 512                           // presorted run length

__device__ __forceinline__ unsigned long long shfl_xor_u64(unsigned long long v, int lx) {
    unsigned int lo = (unsigned int)__shfl_xor((int)(unsigned int)(v & 0xffffffffull), lx, 64);
    unsigned int hi = (unsigned int)__shfl_xor((int)(unsigned int)(v >> 32), lx, 64);
    return ((unsigned long long)hi << 32) | (unsigned long long)lo;
}
__device__ __forceinline__ float readlane_f(float v, int l) {
    return __int_as_float(__builtin_amdgcn_readlane(__float_as_int(v), l));
}
__device__ __forceinline__ unsigned long long readlane_u64(unsigned long long v, int l) {
    unsigned int lo = (unsigned int)__builtin_amdgcn_readlane((int)(unsigned int)(v & 0xffffffffull), l);
    unsigned int hi = (unsigned int)__builtin_amdgcn_readlane((int)(unsigned int)(v >> 32), l);
    return ((unsigned long long)hi << 32) | (unsigned long long)lo;
}
// Exact fp32 replacement for: RN(inter / max(uni,1e-8f)) > 0.5f.
// For floats a>=0, b>0:  RN(a/b) > 0.5  <=>  a+a > b.
// (<=) 2a>b => 2a >= succ(b) = b+ulp(b) > b(1+2^-24) (b*2^-24 < ulp(b))
//      => a/b > 0.5+2^-25 => RN rounds above 0.5.
// (=>) RN(a/b)>0.5 => a/b > 0.5+2^-25 (tie-to-even sends midpoint DOWN to 0.5);
//      2a<=b => a/b<=0.5, contradiction. Midpoint 2a=b(1+2^-24) lies strictly
//      between b and succ(b) -> unrepresentable, so no knife-edge case exists.
__device__ __forceinline__ bool iou_gt_half(float inter, float uni) {
    return inter + inter > fmaxf(uni, 1e-8f);
}
__device__ __forceinline__ float parse_imgf(int raw) {
    return (raw > 0 && raw < 1000000) ? (float)raw : __int_as_float(raw);
}

// ---------------- kernel A: fused decode + 512-run presort ----------------
// 128 blocks: one per (img,cls,quarter). Sorts its run descending iff
// (run_start & 512)==0 (mirrored bitonic network via `flip`) == state of the
// standard full network after stage k=512.
__global__ __launch_bounds__(NTHA)
void decode_sort_kernel(const float* __restrict__ class_logit,
                        const float* __restrict__ box_reg,
                        const float* __restrict__ proposal,
                        const int* __restrict__ image_shape_p,
                        unsigned long long* __restrict__ wskey,   // [2][NUNITS]
                        float2* __restrict__ wbox)                // [2][NUNITS]
{
#pragma clang fp contract(off)
    __shared__ unsigned long long skey[RUN];

    const int tid = threadIdx.x;
    const int lane = tid & 63;
    const int wid = tid >> 6;
    const int u = blockIdx.x >> 2;
    const int q = blockIdx.x & 3;
    const int img = u >> 1;
    const int cls = u & 1;                       // fg class index-1
    const bool flip = (q & 1) != 0;              // odd quarters sort ascending
    const int off = q * RUN;
    const size_t base = (size_t)cls * NUNITS + (size_t)img * N_PROP;
    const float imgf = parse_imgf(image_shape_p[0]);

    // decode 512 proposals for this class (identical fp sequence to reference)
    for (int i = tid; i < RUN; i += NTHA) {
        const int n = off + i;
        const size_t g = (size_t)img * N_PROP + n;
        const float* lg = class_logit + g * C_CLS;
        float l0 = lg[0], l1 = lg[1], l2 = lg[2];
        float mx = fmaxf(l0, fmaxf(l1, l2));
        float e0 = (float)exp((double)(l0 - mx));
        float e1 = (float)exp((double)(l1 - mx));
        float e2 = (float)exp((double)(l2 - mx));
        float denom = (e0 + e1) + e2;
        float score = ((cls == 0) ? e1 : e2) / denom;

        const float* dr = box_reg + g * (2 * C_CLS) + 2 * (cls + 1);
        float dx = dr[0];                       // / WX == 1
        float dw = fminf(dr[1], 4.0f);          // / WW == 1, clamp 4
        const float* pp = proposal + g * 2;
        float pA = pp[0], pB = pp[1];
        float w = pB - pA;
        float ctr = pA + 0.5f * w;
        float tt = dx * w;
        float pc = tt + ctr;
        float pw = (float)exp((double)dw) * w;
        float half = 0.5f * pw;
        float lo = pc - half;
        float hi = pc + half;
        lo = fminf(fmaxf(lo, 0.0f), imgf);
        hi = fminf(fmaxf(hi, 0.0f), imgf);
        bool valid = ((hi - lo) >= 10.0f) && (score >= 0.05f);
        float ms = valid ? score : -1e9f;
        wbox[base + n] = make_float2(lo, hi);
        unsigned int uu = __float_as_uint(ms);
        unsigned int e = (uu & 0x80000000u) ? ~uu : (uu | 0x80000000u); // order-preserving
        skey[i] = ((unsigned long long)e << 32) |
                  (unsigned long long)(0xFFFFFFFFu - (unsigned int)n);  // idx asc on ties
    }
    __syncthreads();

    // hybrid reg/LDS bitonic over the 512-run (direction mirrored by flip)
    const int p0 = (wid << 7) | (lane << 1);    // == 2*tid, wave-contiguous spans
    const int p1 = p0 | 1;
    unsigned long long r0 = skey[p0], r1 = skey[p1];

    auto pass_inreg = [&](int k, int j) {
        bool desc = (((p0 & k) == 0) != flip);
        if (j == 1) {
            bool sw = desc ? (r0 < r1) : (r0 > r1);
            if (sw) { unsigned long long t = r0; r0 = r1; r1 = t; }
        } else {
            int lx = j >> 1;
            unsigned long long o0 = shfl_xor_u64(r0, lx);
            unsigned long long o1 = shfl_xor_u64(r1, lx);
            bool lower = ((p0 & j) == 0);
            bool takeMax = (lower == desc);
            r0 = takeMax ? (r0 > o0 ? r0 : o0) : (r0 < o0 ? r0 : o0);
            r1 = takeMax ? (r1 > o1 ? r1 : o1) : (r1 < o1 ? r1 : o1);
        }
    };

    for (int k = 2; k <= 128; k <<= 1)
        for (int j = k >> 1; j >= 1; j >>= 1)
            pass_inreg(k, j);

    for (int k = 256; k <= RUN; k <<= 1) {
        skey[p0] = r0; skey[p1] = r1;
        __syncthreads();
        for (int j = k >> 1; j >= 128; j >>= 1) {
            int i = ((tid & ~(j - 1)) << 1) | (tid & (j - 1));
            int part = i | j;
            unsigned long long a = skey[i], b = skey[part];
            bool desc_blk = (((i & k) == 0) != flip);
            bool sw = desc_blk ? (a < b) : (a > b);
            if (sw) { skey[i] = b; skey[part] = a; }
            __syncthreads();
        }
        r0 = skey[p0]; r1 = skey[p1];
        for (int j = 64; j >= 1; j >>= 1)
            pass_inreg(k, j);
    }
    wskey[base + off + p0] = r0;
    wskey[base + off + p1] = r1;
}

// ---------------- kernel B: bitonic merge (k=1024,2048) + NMS + top-K ----------------
__global__ __launch_bounds__(NTHREADS)
void roiheads_kernel(const unsigned long long* __restrict__ wskey,
                     const float2* __restrict__ wbox,
                     float* __restrict__ out)
{
#pragma clang fp contract(off)
    __shared__ unsigned long long skey[N_PROP];     // 16 KB sort keys
    __shared__ float slo[N_PROP], shi[N_PROP];      // boxes in sorted order
    __shared__ unsigned char keep[N_PROP];
    __shared__ unsigned short alv[2][N_PROP];       // alive (undecided) sorted positions
    __shared__ float clo[64], chi[64];              // current chunk's kept boxes
    __shared__ unsigned long long sup[64];          // chunk suppression matrix rows
    __shared__ unsigned long long kmask[NBLK64];
    __shared__ int wsum[NWAVES];
    __shared__ int sh_nvalid;

    const int tid = threadIdx.x;
    const int lane = tid & 63;
    const int wid = tid >> 6;
    const int img = blockIdx.x >> 1;
    const int cls = blockIdx.x & 1;
    const size_t base = (size_t)cls * NUNITS + (size_t)img * N_PROP;

    if (tid == 0) sh_nvalid = 0;

    const int p0 = (wid << 7) | (lane << 1);   // == 2*tid
    const int p1 = p0 | 1;

    unsigned long long r0 = wskey[base + p0];  // coalesced 16B/thread
    unsigned long long r1 = wskey[base + p1];

    auto pass_inreg = [&](int k, int j) {
        if (j == 1) {
            bool desc = ((p0 & k) == 0);
            bool sw = desc ? (r0 < r1) : (r0 > r1);
            if (sw) { unsigned long long t = r0; r0 = r1; r1 = t; }
        } else {
            int lx = j >> 1;
            unsigned long long o0 = shfl_xor_u64(r0, lx);
            unsigned long long o1 = shfl_xor_u64(r1, lx);
            bool desc = ((p0 & k) == 0);
            bool lower = ((p0 & j) == 0);
            bool takeMax = (lower == desc);
            r0 = takeMax ? (r0 > o0 ? r0 : o0) : (r0 < o0 ? r0 : o0);
            r1 = takeMax ? (r1 > o1 ? r1 : o1) : (r1 < o1 ? r1 : o1);
        }
    };

    // only the merge stages remain: runs of 512 arrive presorted in
    // alternating directions (network state after stage k=512).
    for (int k = 1024; k <= N_PROP; k <<= 1) {
        skey[p0] = r0; skey[p1] = r1;
        __syncthreads();
        for (int j = k >> 1; j >= 128; j >>= 1) {
            int i = ((tid & ~(j - 1)) << 1) | (tid & (j - 1));
            int part = i | j;
            unsigned long long a = skey[i], b = skey[part];
            bool desc_blk = ((i & k) == 0);
            bool sw = desc_blk ? (a < b) : (a > b);
            if (sw) { skey[i] = b; skey[part] = a; }
            __syncthreads();
        }
        r0 = skey[p0]; r1 = skey[p1];
        for (int j = 64; j >= 1; j >>= 1)
            pass_inreg(k, j);
    }
    skey[p0] = r0; skey[p1] = r1;
    __syncthreads();

    // ---- gather sorted boxes (from ws via L2), count valid, init alive list ----
    for (int i = tid; i < N_PROP; i += NTHREADS) {
        unsigned long long kk = skey[i];
        unsigned int e = (unsigned int)(kk >> 32);
        unsigned int sb = (e & 0x80000000u) ? (e & 0x7FFFFFFFu) : ~e;
        float s = __uint_as_float(sb);
        unsigned int n = 0xFFFFFFFFu - (unsigned int)(kk & 0xFFFFFFFFull);
        float2 bx = wbox[base + n];
        slo[i] = bx.x;
        shi[i] = bx.y;
        keep[i] = 0;
        bool v = (s > -5e8f);    // keep0 = s > 0.5*NEG  (valid items sort first)
        unsigned long long mb = __ballot(v);
        if (lane == 0) atomicAdd(&sh_nvalid, __popcll(mb));
        alv[0][i] = (unsigned short)i;
    }
    __syncthreads();

    int na = sh_nvalid;
    int cur = 0;
    int tk = 0;
    const unsigned long long below = (1ull << lane) - 1ull;

    // ---- greedy NMS: parallel 64x64 suppression matrix + scalar mask resolve ----
    while (na > 0) {
        const int m = (na < 64) ? na : 64;

        unsigned short cp = alv[cur][lane];
        bool cin = (lane < m);
        float qloc = cin ? slo[cp] : 0.0f;
        float qhic = cin ? shi[cp] : 0.0f;

#pragma unroll
        for (int rr4 = 0; rr4 < 4; ++rr4) {
            int rr = (wid << 2) | rr4;
            unsigned long long row = 0;
            if (rr < m) {
                unsigned short rp = alv[cur][rr];     // wave-uniform
                float rlo = slo[rp], rhi = shi[rp];   // broadcast LDS reads
                float inter = fmaxf(fminf(rhi, qhic) - fmaxf(rlo, qloc), 0.0f);
                float uni = (rhi - rlo) + (qhic - qloc) - inter;
                bool kill = cin && (lane > rr) && iou_gt_half(inter, uni);
                row = __ballot(kill);
            }
            if (lane == 0) sup[rr] = row;
        }
        __syncthreads();

        unsigned long long rw = sup[lane];
        unsigned long long A = (m >= 64) ? ~0ull : ((1ull << m) - 1ull);
        unsigned long long kept = 0;
        while (A) {
            int c = __builtin_ctzll(A);
            kept |= (1ull << c);
            A &= ~(readlane_u64(rw, c) | (1ull << c));
        }
        const int cnt = __popcll(kept);

        if (wid == 0) {
            bool alive = cin && ((kept >> lane) & 1ull);
            if (alive) {
                keep[cp] = 1;
                int rank = __popcll(kept & below);
                clo[rank] = qloc; chi[rank] = qhic;
            }
        }
        __syncthreads();
        tk += cnt;
        if (tk >= K_OUT) break;   // later decisions provably unused

        float klo = 0.0f, khi = 0.0f;
        if (lane < cnt) { klo = clo[lane]; khi = chi[lane]; }
        int base2 = 0;
        for (int start = 64; start < na; start += NTHREADS) {
            int t2 = start + tid;
            unsigned short qq = 0;
            bool surv = false;
            bool act = (t2 < na);
            if (act) {
                qq = alv[cur][t2];
                float qlo = slo[qq], qhi = shi[qq];
                float qw = qhi - qlo;
                bool dead = false;
                for (int r = 0; r < cnt; ++r) {
                    float cl = readlane_f(klo, r);
                    float ch = readlane_f(khi, r);
                    float inter = fmaxf(fminf(qhi, ch) - fmaxf(qlo, cl), 0.0f);
                    float uni = qw + (ch - cl) - inter;
                    dead |= iou_gt_half(inter, uni);
                    if ((r & 15) == 15 && __all(dead)) break;  // wave-uniform early out
                }
                surv = !dead;
            }
            unsigned long long mb = __ballot(surv);
            if (lane == 0) wsum[wid] = __popcll(mb);
            __syncthreads();
            int off2 = base2, tot = base2;
            for (int w2 = 0; w2 < NWAVES; ++w2) {
                int c2 = wsum[w2];
                if (w2 < wid) off2 += c2;
                tot += c2;
            }
            if (surv) alv[cur ^ 1][off2 + __popcll(mb & below)] = qq;
            base2 = tot;
            __syncthreads();
        }
        na = base2;
        cur ^= 1;
    }

    // ---- top-K fill (reproduces lax.top_k tie-breaking exactly) ----
    for (int blk = wid; blk < NBLK64; blk += NWAVES) {
        bool kk = keep[blk * 64 + lane] != 0;
        unsigned long long mb = __ballot(kk);
        if (lane == 0) kmask[blk] = mb;
    }
    __syncthreads();
    {
        float* outp = out + (((size_t)img * 2 + cls) * K_OUT) * 3;
        for (int blk = wid; blk < NBLK64; blk += NWAVES) {
            int kc = 0, nc = 0, nk = 0;
            for (int b = 0; b < NBLK64; ++b) {
                int pc = __popcll(kmask[b]);
                nk += pc;
                if (b < blk) { kc += pc; nc += 64 - pc; }
            }
            if (kc >= K_OUT && nk + nc >= K_OUT && nc >= K_OUT) continue;
            int p = blk * 64 + lane;
            unsigned long long mb = kmask[blk];
            bool k = (mb >> lane) & 1ull;
            int rk = kc + __popcll(mb & below);
            int rn = nc + __popcll((~mb) & below);
            if (k) {
                if (rk < K_OUT) {
                    unsigned long long kk2 = skey[p];
                    unsigned int e = (unsigned int)(kk2 >> 32);
                    unsigned int sb = (e & 0x80000000u) ? (e & 0x7FFFFFFFu) : ~e;
                    outp[rk * 3 + 0] = slo[p];
                    outp[rk * 3 + 1] = shi[p];
                    outp[rk * 3 + 2] = __uint_as_float(sb);
                }
            } else {
                int oi = nk + rn;
                if (oi < K_OUT) {
                    outp[oi * 3 + 0] = slo[p];
                    outp[oi * 3 + 1] = shi[p];
                    outp[oi * 3 + 2] = -1e9f;
                }
            }
        }
    }
}

extern "C" void kernel_launch(void* const* d_in, const int* in_sizes, int n_in,
                              void* d_out, int out_size, void* d_ws, size_t ws_size,
                              hipStream_t stream) {
    const float* class_logit = (const float*)d_in[0];
    const float* box_reg     = (const float*)d_in[1];
    const float* prop        = (const float*)d_in[2];
    const int*   image_shape = (const int*)d_in[3];
    float* out = (float*)d_out;

    unsigned long long* wskey = (unsigned long long*)d_ws;            // 512 KB
    float2* wbox = (float2*)((char*)d_ws + 2 * NUNITS * sizeof(unsigned long long));

    decode_sort_kernel<<<dim3(B_IMG * 2 * 4), dim3(NTHA), 0, stream>>>(
        class_logit, box_reg, prop, image_shape, wskey, wbox);
    roiheads_kernel<<<dim3(B_IMG * 2), dim3(NTHREADS), 0, stream>>>(
        wskey, wbox, out);
}